// Round 7
// baseline (339.080 us; speedup 1.0000x reference)
//
#include <hip/hip_runtime.h>

// SobelLoss R7: persistent blocks + independent-iteration depth-2 pipeline.
//
// R2..R6 post-mortem: five structures, all 125-138us. HBM bytes, L2 bytes,
// bank conflicts, per-wave MLP all falsified as predictors. Remaining theory:
// all variants issue loads in per-block bursts (short-lived blocks) or a
// serial chain (R3b); sustained load-ISSUE rate is ~3x short of what LN/
// RMSNorm-shaped kernels (80%+ of copy BW on this chip) achieve with
// persistent independent-iteration streaming loops. R7 = R4's verified math
// inside a persistent 32-row loop with an explicit A/B depth-2 register
// pipeline: issue row r+1's 9-load bundle, compute/store row r from the
// bundle issued one iteration ago. No LDS, no barriers, no carried deps.
//
// Math identical to R4/R5 (passed, absmax 0.03125):
//   d = pred - tgt; hx = dR - dL; hs = dL + 2d + dR (per row)
//   gx = hx(r-1)+2hx(r)+hx(r+1); gy = hs(r+1)-hs(r-1)
//   valid = AND of 3x3 mask; border rows/cols forced 0 via vm=0.

constexpr int H = 512, W = 512, F = 8;
constexpr int IMAGES = 12;                  // B*T
constexpr int QUADS  = 4;                   // 128-pixel spans per row
constexpr int RG     = 32;                  // output rows per block
constexpr int NGRP   = H / RG;              // 16
constexpr int NB     = IMAGES * QUADS * NGRP;   // 768 (div by 8)

typedef float f32x4 __attribute__((ext_vector_type(4)));

__global__ __launch_bounds__(256) void sobel_loss_kernel(
    const float* __restrict__ pred,
    const float* __restrict__ tgt,
    const int*   __restrict__ mask,
    float*       __restrict__ out)
{
    const int tid  = threadIdx.x;
    const int lane = tid & 63;
    const int wid  = tid >> 6;

    // XCD swizzle (NB % 8 == 0, bijective). Post-swizzle consecutive bids =
    // consecutive row-groups of the same (img,quad) strip -> each XCD owns
    // contiguous vertical bands; halo rows stay L2/L3-local.
    const int b0  = blockIdx.x;
    const int bid = (b0 & 7) * (NB >> 3) + (b0 >> 3);

    const int img  = bid >> 6;              // / (QUADS*NGRP)
    const int rest = bid & 63;
    const int quad = rest >> 4;
    const int grp  = rest & 15;
    const int r0   = grp * RG;

    const int p = lane >> 1;                // pixel within wave's 32-px span
    const int q = lane & 1;                 // float4 half
    const int w = quad * 128 + wid * 32 + p;

    const size_t ibase = (size_t)img * ((size_t)H * W * F);
    const int voff = w * F + q * 4;

    const bool eL = (p == 0);
    const bool eR = (p == 31);
    const bool edge = eL || eR;
    const int  wn  = eL ? (w > 0 ? w - 1 : 0) : (w < W - 1 ? w + 1 : W - 1);
    const int  eoff = wn * F + q * 4;
    const bool win  = (w > 0) & (w < W - 1);

#define SUB4(a, b) make_float4((a).x - (b).x, (a).y - (b).y, (a).z - (b).z, (a).w - (b).w)
#define PACK(M) ((unsigned)((M).x | ((M).y << 1) | ((M).z << 2) | ((M).w << 3)))

    // A/B register bundles (9 x 16B each): the depth-2 pipeline state.
#define DECLBUF(S) float4 P0##S, P1##S, P2##S, T0##S, T1##S, T2##S; \
                   int4   M0##S, M1##S, M2##S;
    DECLBUF(A)
    DECLBUF(B)

    // Issue the 9 independent main loads for output row R into bundle S.
#define LOADBUF(S, R)                                                         \
    {                                                                         \
        const int r_ = (R);                                                   \
        const int ra = (r_ - 1 < 0) ? 0 : r_ - 1;                             \
        const int rc = (r_ + 1 > H - 1) ? H - 1 : r_ + 1;                     \
        const size_t o0 = ibase + (size_t)ra * (W * F) + voff;                \
        const size_t o1 = ibase + (size_t)r_ * (W * F) + voff;                \
        const size_t o2 = ibase + (size_t)rc * (W * F) + voff;                \
        P0##S = *(const float4*)(pred + o0);                                  \
        P1##S = *(const float4*)(pred + o1);                                  \
        P2##S = *(const float4*)(pred + o2);                                  \
        T0##S = *(const float4*)(tgt  + o0);                                  \
        T1##S = *(const float4*)(tgt  + o1);                                  \
        T2##S = *(const float4*)(tgt  + o2);                                  \
        M0##S = *(const int4*)(mask + o0);                                    \
        M1##S = *(const int4*)(mask + o1);                                    \
        M2##S = *(const int4*)(mask + o2);                                    \
    }

#define ROWOP(P, T, M, EP, ET, EM, HX, HS, HM)                                \
    {                                                                         \
        const float4 d  = SUB4(P, T);                                         \
        const float4 ed = SUB4(EP, ET);                                       \
        const unsigned m  = PACK(M);                                          \
        const unsigned em = PACK(EM);                                         \
        float4 dl, dr;                                                        \
        dl.x = __shfl_up(d.x, 2);   dl.y = __shfl_up(d.y, 2);                 \
        dl.z = __shfl_up(d.z, 2);   dl.w = __shfl_up(d.w, 2);                 \
        dr.x = __shfl_down(d.x, 2); dr.y = __shfl_down(d.y, 2);               \
        dr.z = __shfl_down(d.z, 2); dr.w = __shfl_down(d.w, 2);               \
        unsigned ml = (unsigned)__shfl_up((int)m, 2);                         \
        unsigned mr = (unsigned)__shfl_down((int)m, 2);                       \
        if (eL) { dl = ed; ml = em; }                                         \
        if (eR) { dr = ed; mr = em; }                                         \
        HX = SUB4(dr, dl);                                                    \
        HS = make_float4(dl.x + 2.f * d.x + dr.x,                             \
                         dl.y + 2.f * d.y + dr.y,                             \
                         dl.z + 2.f * d.z + dr.z,                             \
                         dl.w + 2.f * d.w + dr.w);                            \
        HM = ml & m & mr;                                                     \
    }

    // Consume bundle S, compute + store output row R. Edge-lane neighbor
    // loads (4/64 lanes, L2-hot) issued at the top so their latency overlaps
    // the main VALU work.
#define COMPUTE(S, R)                                                         \
    {                                                                         \
        const int r_ = (R);                                                   \
        const int ra = (r_ - 1 < 0) ? 0 : r_ - 1;                             \
        const int rc = (r_ + 1 > H - 1) ? H - 1 : r_ + 1;                     \
        float4 EP0, EP1, EP2, ET0, ET1, ET2;                                  \
        int4   EM0, EM1, EM2;                                                 \
        EP0 = EP1 = EP2 = ET0 = ET1 = ET2 = make_float4(0.f, 0.f, 0.f, 0.f);  \
        EM0 = EM1 = EM2 = make_int4(0, 0, 0, 0);                              \
        if (edge) {                                                           \
            const size_t e0 = ibase + (size_t)ra * (W * F) + eoff;            \
            const size_t e1 = ibase + (size_t)r_ * (W * F) + eoff;            \
            const size_t e2 = ibase + (size_t)rc * (W * F) + eoff;            \
            EP0 = *(const float4*)(pred + e0);                                \
            EP1 = *(const float4*)(pred + e1);                                \
            EP2 = *(const float4*)(pred + e2);                                \
            ET0 = *(const float4*)(tgt  + e0);                                \
            ET1 = *(const float4*)(tgt  + e1);                                \
            ET2 = *(const float4*)(tgt  + e2);                                \
            EM0 = *(const int4*)(mask + e0);                                  \
            EM1 = *(const int4*)(mask + e1);                                  \
            EM2 = *(const int4*)(mask + e2);                                  \
        }                                                                     \
        float4 hx0, hx1, hx2, hs0, hs1, hs2;                                  \
        unsigned hm0, hm1, hm2;                                               \
        ROWOP(P0##S, T0##S, M0##S, EP0, ET0, EM0, hx0, hs0, hm0)              \
        ROWOP(P1##S, T1##S, M1##S, EP1, ET1, EM1, hx1, hs1, hm1)              \
        ROWOP(P2##S, T2##S, M2##S, EP2, ET2, EM2, hx2, hs2, hm2)              \
        unsigned vm = hm0 & hm1 & hm2;                                        \
        if (!win || r_ == 0 || r_ == H - 1) vm = 0u;                          \
        f32x4 o;                                                              \
        { const float gx = hx0.x + 2.f * hx1.x + hx2.x;                       \
          const float gy = hs2.x - hs0.x;                                     \
          o.x = (vm & 1u) ? (fabsf(gx) + fabsf(gy)) : 0.f; }                  \
        { const float gx = hx0.y + 2.f * hx1.y + hx2.y;                       \
          const float gy = hs2.y - hs0.y;                                     \
          o.y = (vm & 2u) ? (fabsf(gx) + fabsf(gy)) : 0.f; }                  \
        { const float gx = hx0.z + 2.f * hx1.z + hx2.z;                       \
          const float gy = hs2.z - hs0.z;                                     \
          o.z = (vm & 4u) ? (fabsf(gx) + fabsf(gy)) : 0.f; }                  \
        { const float gx = hx0.w + 2.f * hx1.w + hx2.w;                       \
          const float gy = hs2.w - hs0.w;                                     \
          o.w = (vm & 8u) ? (fabsf(gx) + fabsf(gy)) : 0.f; }                  \
        *(f32x4*)(out + ibase + (size_t)r_ * (W * F) + voff) = o;             \
    }

    // ---- persistent 32-row loop, depth-2 A/B pipeline, 2 rows/iter --------
    LOADBUF(A, r0)                          // prologue: row r0 into A
#pragma unroll 1
    for (int i = 0; i < RG; i += 2) {
        const int r = r0 + i;
        LOADBUF(B, r + 1)                   // issue next row's bundle
        COMPUTE(A, r)                       // consume bundle issued 1 iter ago
        if (i + 2 < RG) LOADBUF(A, r + 2)   // issue row after next
        COMPUTE(B, r + 1)
    }

#undef COMPUTE
#undef ROWOP
#undef LOADBUF
#undef DECLBUF
#undef PACK
#undef SUB4
}

extern "C" void kernel_launch(void* const* d_in, const int* in_sizes, int n_in,
                              void* d_out, int out_size, void* d_ws, size_t ws_size,
                              hipStream_t stream) {
    const float* pred = (const float*)d_in[0];
    const float* tgt  = (const float*)d_in[1];
    const int*   mask = (const int*)d_in[2];
    float*       out  = (float*)d_out;

    sobel_loss_kernel<<<NB, 256, 0, stream>>>(pred, tgt, mask, out);
}

// Round 8
// 331.469 us; speedup vs baseline: 1.0230x; 1.0230x over previous
//
#include <hip/hip_runtime.h>

// SobelLoss R8: ZERO ds-pipe usage — no LDS, no __shfl (ds_bpermute), nothing.
//
// R2..R7 post-mortem: six structures, 125-155us, no saturated pipe, and the
// one shared trait is that horizontal-neighbor exchange always went through
// the LDS hardware (ds_read tiles or ds_bpermute shuffles, both lgkmcnt).
// Estimated LDS-pipe serialization accounts for 50-75% of kernel time in
// R6/R2; R7's occupancy-drop regression matches an LDS-latency bound.
// R8 reloads L/R neighbors from GLOBAL at voff +/- F (L1/MSHR hits: the
// center load just touched 15/17 of those lines). 27 independent 16B loads
// per thread, wave-uniform row bases (SGPR) + 3 per-lane voffsets. No
// special span-edge handling needed (global loads cross spans naturally).
// Validity = direct 9-way int4 AND (mask values are 0/1).
//
// Math identical to R4..R7 (all passed, absmax 0.03125):
//   d = pred - tgt; per row: hx = dR - dL, hs = dL + 2d + dR
//   gx = hx0 + 2 hx1 + hx2; gy = hs2 - hs0
//   valid = AND of 3x3 mask; border rows/cols forced 0.

constexpr int H = 512, W = 512, F = 8;
constexpr int IMAGES = 12;               // B*T
constexpr int NB = IMAGES * H * 4;       // 24576 blocks (4 quads of 128 px/row)

typedef float f32x4 __attribute__((ext_vector_type(4)));

__global__ __launch_bounds__(256) void sobel_loss_kernel(
    const float* __restrict__ pred,
    const float* __restrict__ tgt,
    const int*   __restrict__ mask,
    float*       __restrict__ out)
{
    const int tid = threadIdx.x;

    // XCD-contiguous bijective swizzle (NB % 8 == 0): each XCD owns a
    // contiguous (img,row) band -> 3x vertical row re-reads stay in its L2.
    const int b0  = blockIdx.x;
    const int bid = (b0 & 7) * (NB >> 3) + (b0 >> 3);

    const int img  = bid >> 11;          // 2048 blocks per image
    const int rest = bid & 2047;
    const int r    = rest >> 2;          // row 0..511
    const int quad = rest & 3;           // 128-pixel quarter of the row

    const int w = quad * 128 + (tid >> 1);   // consecutive tid -> consecutive 16B
    const int q = tid & 1;

    const size_t ibase = (size_t)img * ((size_t)H * W * F);
    const int voff = w * F + q * 4;
    float* const op = out + ibase + (size_t)r * (W * F) + voff;

    if (r == 0 || r == H - 1) {          // border rows: valid == 0 everywhere
        f32x4 z = {0.f, 0.f, 0.f, 0.f};
        __builtin_nontemporal_store(z, (f32x4*)op);
        return;
    }

    const bool win = (w > 0) & (w < W - 1);
    // In-bounds clamped L/R offsets (values only used when win; vm=0 else).
    const int lo = win ? voff - F : voff;
    const int ro = win ? voff + F : voff;

    // Wave-uniform row bases (r is block-uniform; ra/rc in-range since
    // 1 <= r <= H-2).
    const float* const rp0 = pred + ibase + (size_t)(r - 1) * (W * F);
    const float* const rp1 = pred + ibase + (size_t)(r    ) * (W * F);
    const float* const rp2 = pred + ibase + (size_t)(r + 1) * (W * F);
    const float* const rt0 = tgt  + ibase + (size_t)(r - 1) * (W * F);
    const float* const rt1 = tgt  + ibase + (size_t)(r    ) * (W * F);
    const float* const rt2 = tgt  + ibase + (size_t)(r + 1) * (W * F);
    const int*   const rm0 = mask + ibase + (size_t)(r - 1) * (W * F);
    const int*   const rm1 = mask + ibase + (size_t)(r    ) * (W * F);
    const int*   const rm2 = mask + ibase + (size_t)(r + 1) * (W * F);

    // ---- 27 independent 16B loads (L/R are L1/MSHR hits off the C lines) --
    const float4 pL0 = *(const float4*)(rp0 + lo);
    const float4 pC0 = *(const float4*)(rp0 + voff);
    const float4 pR0 = *(const float4*)(rp0 + ro);
    const float4 pL1 = *(const float4*)(rp1 + lo);
    const float4 pC1 = *(const float4*)(rp1 + voff);
    const float4 pR1 = *(const float4*)(rp1 + ro);
    const float4 pL2 = *(const float4*)(rp2 + lo);
    const float4 pC2 = *(const float4*)(rp2 + voff);
    const float4 pR2 = *(const float4*)(rp2 + ro);

    const float4 tL0 = *(const float4*)(rt0 + lo);
    const float4 tC0 = *(const float4*)(rt0 + voff);
    const float4 tR0 = *(const float4*)(rt0 + ro);
    const float4 tL1 = *(const float4*)(rt1 + lo);
    const float4 tC1 = *(const float4*)(rt1 + voff);
    const float4 tR1 = *(const float4*)(rt1 + ro);
    const float4 tL2 = *(const float4*)(rt2 + lo);
    const float4 tC2 = *(const float4*)(rt2 + voff);
    const float4 tR2 = *(const float4*)(rt2 + ro);

    const int4 mL0 = *(const int4*)(rm0 + lo);
    const int4 mC0 = *(const int4*)(rm0 + voff);
    const int4 mR0 = *(const int4*)(rm0 + ro);
    const int4 mL1 = *(const int4*)(rm1 + lo);
    const int4 mC1 = *(const int4*)(rm1 + voff);
    const int4 mR1 = *(const int4*)(rm1 + ro);
    const int4 mL2 = *(const int4*)(rm2 + lo);
    const int4 mC2 = *(const int4*)(rm2 + voff);
    const int4 mR2 = *(const int4*)(rm2 + ro);

    // ---- validity: 9-way AND per channel (mask values are 0/1) ----
    int4 vm4;
    vm4.x = mL0.x & mC0.x & mR0.x & mL1.x & mC1.x & mR1.x & mL2.x & mC2.x & mR2.x;
    vm4.y = mL0.y & mC0.y & mR0.y & mL1.y & mC1.y & mR1.y & mL2.y & mC2.y & mR2.y;
    vm4.z = mL0.z & mC0.z & mR0.z & mL1.z & mC1.z & mR1.z & mL2.z & mC2.z & mR2.z;
    vm4.w = mL0.w & mC0.w & mR0.w & mL1.w & mC1.w & mR1.w & mL2.w & mC2.w & mR2.w;
    const int inw = win ? ~0 : 0;
    vm4.x &= inw; vm4.y &= inw; vm4.z &= inw; vm4.w &= inw;

    f32x4 o;
#define COMP(cc)                                                               \
    {                                                                          \
        const float dL0 = pL0.cc - tL0.cc, dC0 = pC0.cc - tC0.cc,              \
                    dR0 = pR0.cc - tR0.cc;                                     \
        const float dL1 = pL1.cc - tL1.cc, dC1 = pC1.cc - tC1.cc,              \
                    dR1 = pR1.cc - tR1.cc;                                     \
        const float dL2 = pL2.cc - tL2.cc, dC2 = pC2.cc - tC2.cc,              \
                    dR2 = pR2.cc - tR2.cc;                                     \
        const float hx0 = dR0 - dL0;                                           \
        const float hx1 = dR1 - dL1;                                           \
        const float hx2 = dR2 - dL2;                                           \
        const float hs0 = dL0 + 2.f * dC0 + dR0;                               \
        const float hs2 = dL2 + 2.f * dC2 + dR2;                               \
        const float gx = hx0 + 2.f * hx1 + hx2;                                \
        const float gy = hs2 - hs0;                                            \
        o.cc = vm4.cc ? (fabsf(gx) + fabsf(gy)) : 0.f;                         \
    }
    COMP(x) COMP(y) COMP(z) COMP(w)
#undef COMP

    __builtin_nontemporal_store(o, (f32x4*)op);
}

extern "C" void kernel_launch(void* const* d_in, const int* in_sizes, int n_in,
                              void* d_out, int out_size, void* d_ws, size_t ws_size,
                              hipStream_t stream) {
    const float* pred = (const float*)d_in[0];
    const float* tgt  = (const float*)d_in[1];
    const int*   mask = (const int*)d_in[2];
    float*       out  = (float*)d_out;

    sobel_loss_kernel<<<NB, 256, 0, stream>>>(pred, tgt, mask, out);
}

// Round 9
// 310.465 us; speedup vs baseline: 1.0922x; 1.0677x over previous
//
#include <hip/hip_runtime.h>

// SobelLoss R9: persistent column-strip walker, 10-row LDS ring, T14 overlap.
//
// R2..R8 post-mortem: eight structures, 125-155us; HBM bytes, L2 bytes, MLP,
// bank conflicts, ds-pipe, persistence all individually falsified. Remaining
// model: per-wave PHASE SERIALIZATION (load-wait-compute-store) with partial
// cross-wave overlap sums to ~2x the 64us traffic floor in every variant.
// R9 overlaps phases within each wave continuously: per 8-row step, issue
// next rows' global loads into registers FIRST, compute current 8 output
// rows from the LDS ring (covers global latency), then barrier + ds_write
// the staged rows into the ring + barrier. Ring keeps the 2 overlap rows ->
// each input byte is read exactly once (1.06x traffic incl. halo).
//
// Geometry: block = 256 thr (4 waves) owns a 64px x 64row strip.
//   ring = 10 rows x 132 units (unit = 16B = half-pixel): d=pred-tgt float4
//   + packed 4-bit mask. Units 0,1 / 130,131 are +/-1-pixel horizontal halo.
// Grid = 12 img x 8 spans x 8 vchunks = 768 blocks = 3/CU, all co-resident.
//
// Math identical to R6 (passed, absmax 0.03125):
//   per row: hx = dR - dL, hs = dL + 2d + dR
//   gx = hx0 + 2 hx1 + hx2; gy = hs2 - hs0
//   valid = AND of 3x3 packed mask; OOB rows/cols staged with mask=0 so
//   borders fall out to 0 with no special-casing in compute.

constexpr int H = 512, W = 512, F = 8;
constexpr int IMAGES = 12;             // B*T
constexpr int SPAN  = 64;              // pixels per strip
constexpr int NSPAN = W / SPAN;        // 8
constexpr int VCH   = 64;              // rows per block
constexpr int NVCH  = H / VCH;         // 8
constexpr int NB    = IMAGES * NSPAN * NVCH;  // 768
constexpr int RING  = 10;              // ring rows
constexpr int STEP  = 8;               // rows per iteration
constexpr int ITERS = VCH / STEP;      // 8
constexpr int UROW  = 2 * SPAN + 4;    // 132 16B-units per ring row

typedef float f32x4 __attribute__((ext_vector_type(4)));

struct RowReg {                        // one staged row (per-lane share)
    float4 p0, p1, t0, t1, hp, ht;
    int4   m0, m1, hm;
};

__device__ __forceinline__ int pack4(const int4 m) {
    return m.x | (m.y << 1) | (m.z << 2) | (m.w << 3);
}

__device__ __forceinline__ float4 sub4(const float4 a, const float4 b) {
    return make_float4(a.x - b.x, a.y - b.y, a.z - b.z, a.w - b.w);
}

__device__ __forceinline__ void row_load(
    RowReg& R, const float* __restrict__ pred, const float* __restrict__ tgt,
    const int* __restrict__ mask, size_t ibase, int gr, int w0, int l)
{
    const int grc = gr < 0 ? 0 : (gr > H - 1 ? H - 1 : gr);
    const size_t rb = ibase + (size_t)grc * (W * F) + (size_t)w0 * F;
    const int lo = l * 4;
    R.p0 = *(const float4*)(pred + rb + lo);
    R.p1 = *(const float4*)(pred + rb + lo + 256);
    R.t0 = *(const float4*)(tgt  + rb + lo);
    R.t1 = *(const float4*)(tgt  + rb + lo + 256);
    R.m0 = *(const int4*)(mask + rb + lo);
    R.m1 = *(const int4*)(mask + rb + lo + 256);
    R.hp = make_float4(0.f, 0.f, 0.f, 0.f);
    R.ht = R.hp;
    R.hm = make_int4(0, 0, 0, 0);
    if (l < 4) {                        // horizontal halo: lanes 0..3
        const int side = l >> 1, hq = l & 1;
        const int px  = side ? w0 + SPAN : w0 - 1;
        const int pxc = px < 0 ? 0 : (px > W - 1 ? W - 1 : px);
        const size_t hb = ibase + (size_t)grc * (W * F) + (size_t)pxc * F + hq * 4;
        R.hp = *(const float4*)(pred + hb);
        R.ht = *(const float4*)(tgt  + hb);
        R.hm = *(const int4*)(mask + hb);
    }
}

__device__ __forceinline__ void row_write(
    const RowReg& R, float4* __restrict__ dls, unsigned* __restrict__ mls,
    int slot, int gr, int w0, int l)
{
    const bool rv = (gr >= 0) & (gr < H);
    float4*   drow = dls + slot * UROW;
    unsigned* mrow = mls + slot * UROW;
    drow[2 + l]  = sub4(R.p0, R.t0);
    drow[66 + l] = sub4(R.p1, R.t1);
    mrow[2 + l]  = rv ? (unsigned)pack4(R.m0) : 0u;
    mrow[66 + l] = rv ? (unsigned)pack4(R.m1) : 0u;
    if (l < 4) {
        const int side = l >> 1, hq = l & 1;
        const int px = side ? w0 + SPAN : w0 - 1;
        const bool ib = (px >= 0) & (px < W);
        const int u = side ? (2 + 2 * SPAN + hq) : hq;   // 130,131 / 0,1
        drow[u] = sub4(R.hp, R.ht);
        mrow[u] = (rv && ib) ? (unsigned)pack4(R.hm) : 0u;
    }
}

__global__ __launch_bounds__(256, 3) void sobel_loss_kernel(
    const float* __restrict__ pred,
    const float* __restrict__ tgt,
    const int*   __restrict__ mask,
    float*       __restrict__ out)
{
    __shared__ float4   dls[RING * UROW];   // 21,120 B
    __shared__ unsigned mls[RING * UROW];   //  5,280 B

    const int tid = threadIdx.x;
    const int l   = tid & 63;
    const int wv  = tid >> 6;

    const int bid  = blockIdx.x;
    const int img  = bid >> 6;              // / (NSPAN*NVCH)
    const int rest = bid & 63;
    const int span = rest >> 3;
    const int vch  = rest & 7;              // vch fastest: vertical neighbors adjacent
    const int w0   = span * SPAN;
    const int v0   = vch * VCH;

    const size_t ibase = (size_t)img * ((size_t)H * W * F);

    // ---- prologue: stage ring rows v0-1 .. v0+8 into slots 0..9 ----
    for (int j = wv; j < RING; j += 4) {
        RowReg R;
        row_load(R, pred, tgt, mask, ibase, v0 - 1 + j, w0, l);
        row_write(R, dls, mls, j, v0 - 1 + j, w0, l);
    }
    __syncthreads();

    int bs = 0;                             // (STEP*k) % RING
    for (int k = 0; k < ITERS; ++k) {
        const bool more = (k + 1) < ITERS;
        const int  ja = 2 * wv, jb = 2 * wv + 1;
        const int  gra = v0 + STEP * k + 9 + ja;
        const int  grb = v0 + STEP * k + 9 + jb;

        // (a) issue next batch's global loads -> regs (no waits here)
        RowReg RA, RB;
        if (more) {
            row_load(RA, pred, tgt, mask, ibase, gra, w0, l);
            row_load(RB, pred, tgt, mask, ibase, grb, w0, l);
        }
        __builtin_amdgcn_sched_barrier(0);

        // (b) compute 8 output rows x 128 units from the ring
        const int o0 = v0 + STEP * k;
#pragma unroll
        for (int p = 0; p < 4; ++p) {
            const int item = tid + 256 * p;      // 0..1023
            const int lr = item >> 7;            // row in step 0..7 (wave-uniform)
            const int uo = item & 127;           // output unit in row
            int sB = bs + lr + 1; if (sB >= RING) sB -= RING;   // row r
            int sA = sB - 1;      if (sA < 0)     sA += RING;   // row r-1
            int sC = sB + 1;      if (sC >= RING) sC -= RING;   // row r+1
            const int cu = 2 + uo;

            const float4 a0 = dls[sA * UROW + cu - 2];
            const float4 a1 = dls[sA * UROW + cu];
            const float4 a2 = dls[sA * UROW + cu + 2];
            const float4 b0 = dls[sB * UROW + cu - 2];
            const float4 b1 = dls[sB * UROW + cu];
            const float4 b2 = dls[sB * UROW + cu + 2];
            const float4 c0 = dls[sC * UROW + cu - 2];
            const float4 c1 = dls[sC * UROW + cu];
            const float4 c2 = dls[sC * UROW + cu + 2];

            const unsigned vm =
                mls[sA * UROW + cu - 2] & mls[sA * UROW + cu] & mls[sA * UROW + cu + 2] &
                mls[sB * UROW + cu - 2] & mls[sB * UROW + cu] & mls[sB * UROW + cu + 2] &
                mls[sC * UROW + cu - 2] & mls[sC * UROW + cu] & mls[sC * UROW + cu + 2];

            f32x4 o;
#define COMP(cc, bit)                                                          \
            {                                                                  \
                const float hx0 = a2.cc - a0.cc;                               \
                const float hx1 = b2.cc - b0.cc;                               \
                const float hx2 = c2.cc - c0.cc;                               \
                const float hs0 = a0.cc + 2.f * a1.cc + a2.cc;                 \
                const float hs2 = c0.cc + 2.f * c1.cc + c2.cc;                 \
                const float gx = hx0 + 2.f * hx1 + hx2;                        \
                const float gy = hs2 - hs0;                                    \
                o.cc = (vm & (1u << bit)) ? (fabsf(gx) + fabsf(gy)) : 0.f;     \
            }
            COMP(x, 0) COMP(y, 1) COMP(z, 2) COMP(w, 3)
#undef COMP

            *(f32x4*)(out + ibase + (size_t)(o0 + lr) * (W * F)
                          + (size_t)w0 * F + uo * 4) = o;
        }

        __syncthreads();                     // all ring reads done
        // (c) write staged rows into ring (vmcnt wait lands here, after compute)
        if (more) {
            int wsA = bs + ja; if (wsA >= RING) wsA -= RING;
            int wsB = bs + jb; if (wsB >= RING) wsB -= RING;
            row_write(RA, dls, mls, wsA, gra, w0, l);
            row_write(RB, dls, mls, wsB, grb, w0, l);
        }
        __syncthreads();                     // ring writes visible

        bs += STEP; if (bs >= RING) bs -= RING;
    }
}

extern "C" void kernel_launch(void* const* d_in, const int* in_sizes, int n_in,
                              void* d_out, int out_size, void* d_ws, size_t ws_size,
                              hipStream_t stream) {
    const float* pred = (const float*)d_in[0];
    const float* tgt  = (const float*)d_in[1];
    const int*   mask = (const int*)d_in[2];
    float*       out  = (float*)d_out;

    sobel_loss_kernel<<<NB, 256, 0, stream>>>(pred, tgt, mask, out);
}